// Round 2
// baseline (845.671 us; speedup 1.0000x reference)
//
#include <hip/hip_runtime.h>
#include <math.h>

#define NN 32768
#define NE 65536

__device__ __forceinline__ float elu_f(float v) {
    return v > 0.f ? v : (expf(v) - 1.f);
}

#define FMA8(Cj, aj, b0, b1) \
    Cj[0] += (aj)*(b0).x; Cj[1] += (aj)*(b0).y; Cj[2] += (aj)*(b0).z; Cj[3] += (aj)*(b0).w; \
    Cj[4] += (aj)*(b1).x; Cj[5] += (aj)*(b1).y; Cj[6] += (aj)*(b1).z; Cj[7] += (aj)*(b1).w;

// ---------------- count incoming edges per node ----------------
__global__ void k_cnt(const int* __restrict__ ei, float* __restrict__ cnt) {
    int e = blockIdx.x * 256 + threadIdx.x;
    if (e < NE) atomicAdd(&cnt[ei[NE + e]], 1.f);
}

// ---------------- layer-1 edge messages (NNConv1) ----------------
// msg1[e,o] = sum_i x[src,i] * ( sum_k relu(ea@W1a+b1a)[k] * W1b[k,i*64+o] + b1b[i*64+o] )
// 256 edges/block, 8e x 8o per thread, W1b fully in LDS.
__global__ __launch_bounds__(256, 2) void k1_conv1(
    const float* __restrict__ x, const int* __restrict__ ei,
    const float* __restrict__ eatt,
    const float* __restrict__ W1a, const float* __restrict__ b1a,
    const float* __restrict__ W1b, const float* __restrict__ b1b,
    float* __restrict__ sum1)
{
    __shared__ float sW1b[64 * 192];   // 48 KB
    __shared__ float sb1b[192];
    __shared__ float sW1a[192];
    __shared__ float sb1a[64];
    __shared__ float sxs[256 * 4];
    __shared__ float sea[256 * 4];
    __shared__ int   sdst[256];
    const int tid = threadIdx.x;
    const int e0 = blockIdx.x * 256;

    for (int u = tid; u < 64 * 192 / 4; u += 256)
        ((float4*)sW1b)[u] = ((const float4*)W1b)[u];
    if (tid < 192) { sW1a[tid] = W1a[tid]; sb1b[tid] = b1b[tid]; }
    if (tid < 64)  sb1a[tid] = b1a[tid];
    {
        int e = e0 + tid;
        int s = ei[e];
        sdst[tid] = ei[NE + e];
        sxs[tid*4+0] = x[s*3+0];
        sxs[tid*4+1] = x[s*3+1];
        sxs[tid*4+2] = x[s*3+2];
        sea[tid*4+0] = eatt[e*3+0];
        sea[tid*4+1] = eatt[e*3+1];
        sea[tid*4+2] = eatt[e*3+2];
    }
    __syncthreads();

    const int ty = tid >> 3;       // 0..31  -> 8 edges each
    const int tx = tid & 7;        // 8 o's each
    const int eb = ty * 8;
    const int o0 = tx * 8;

    float xs_r[8][3], ea_r[8][3];
    #pragma unroll
    for (int j = 0; j < 8; ++j)
        #pragma unroll
        for (int i = 0; i < 3; ++i) {
            xs_r[j][i] = sxs[(eb + j) * 4 + i];
            ea_r[j][i] = sea[(eb + j) * 4 + i];
        }

    float C[8][8];
    #pragma unroll
    for (int j = 0; j < 8; ++j)
        #pragma unroll
        for (int l = 0; l < 8; ++l) C[j][l] = 0.f;

    for (int k = 0; k < 64; ++k) {
        float hh[8];
        #pragma unroll
        for (int j = 0; j < 8; ++j) {
            float h = sb1a[k] + ea_r[j][0]*sW1a[k] + ea_r[j][1]*sW1a[64+k] + ea_r[j][2]*sW1a[128+k];
            hh[j] = fmaxf(h, 0.f);
        }
        #pragma unroll
        for (int i = 0; i < 3; ++i) {
            const float4* wp = (const float4*)&sW1b[k*192 + i*64 + o0];
            float4 w0 = wp[0], w1 = wp[1];
            float a[8];
            #pragma unroll
            for (int j = 0; j < 8; ++j) a[j] = hh[j] * xs_r[j][i];
            #pragma unroll
            for (int j = 0; j < 8; ++j) { FMA8(C[j], a[j], w0, w1); }
        }
    }
    // bias term: += sum_i xs[i] * b1b[i*64+o]
    #pragma unroll
    for (int i = 0; i < 3; ++i) {
        const float4* wp = (const float4*)&sb1b[i*64 + o0];
        float4 w0 = wp[0], w1 = wp[1];
        #pragma unroll
        for (int j = 0; j < 8; ++j) {
            float a = xs_r[j][i];
            FMA8(C[j], a, w0, w1);
        }
    }
    #pragma unroll
    for (int j = 0; j < 8; ++j) {
        float* p = sum1 + (long)sdst[eb + j] * 64 + o0;
        #pragma unroll
        for (int l = 0; l < 8; ++l) atomicAdd(p + l, C[j][l]);
    }
}

// ---------------- layer-1 node update ----------------
__global__ void k2_node1(const float* __restrict__ sum1, const float* __restrict__ cnt,
                         const float* __restrict__ x, const float* __restrict__ root1,
                         const float* __restrict__ bias1, float* __restrict__ h1)
{
    int g = blockIdx.x * 256 + threadIdx.x;    // NN*64 threads
    int n = g >> 6, o = g & 63;
    float inv = 1.f / fmaxf(cnt[n], 1.f);
    float v = sum1[g] * inv + bias1[o];
    v += x[n*3+0]*root1[o] + x[n*3+1]*root1[64+o] + x[n*3+2]*root1[128+o];
    h1[g] = elu_f(v);
}

// ---------------- layer-2 edge messages (NNConv2) — the big GEMM ----------------
// C[e,o] = sum_{k<64} h2a[e,k] * (sum_i h1[src,i]*W2b[k,i*64+o])  +  sum_i h1[src,i]*b2b[i*64+o]
// 256 edges/block, 8e x 8o per thread. X^T (gathered h1) resident in LDS for whole K-loop;
// B streams 16KB/k double-buffered from L2; h2a recomputed on the fly (3 FMA + relu per (e,k)).
__global__ __launch_bounds__(256, 1) void k3_conv2(
    const float* __restrict__ h1, const int* __restrict__ ei,
    const float* __restrict__ eatt,
    const float* __restrict__ W2a, const float* __restrict__ b2a,
    const float* __restrict__ W2b, const float* __restrict__ b2b,
    float* __restrict__ sum2)
{
    __shared__ float sXT[64 * 260];     // 66.5 KB : [i][e], pad 260 (bank-spread, 16B-aligned rows)
    __shared__ float sB[2][64 * 64];    // 32 KB double buffer
    __shared__ float sea[256 * 4];
    __shared__ float sW2a[192];
    __shared__ float sb2a[64];
    __shared__ int   ssrc[256];
    __shared__ int   sdst[256];
    const int tid = threadIdx.x;
    const int e0 = blockIdx.x * 256;

    if (tid < 192) sW2a[tid] = W2a[tid];
    if (tid < 64)  sb2a[tid] = b2a[tid];
    {
        int e = e0 + tid;
        ssrc[tid] = ei[e];
        sdst[tid] = ei[NE + e];
        sea[tid*4+0] = eatt[e*3+0];
        sea[tid*4+1] = eatt[e*3+1];
        sea[tid*4+2] = eatt[e*3+2];
    }
    __syncthreads();
    // gather X^T: each thread owns edge e=tid, loads its 64-float h1 row as 16 float4s
    {
        const float* row = h1 + (long)ssrc[tid] * 64;
        #pragma unroll
        for (int it = 0; it < 16; ++it) {
            float4 v = *(const float4*)(row + it * 4);
            sXT[(it*4+0)*260 + tid] = v.x;
            sXT[(it*4+1)*260 + tid] = v.y;
            sXT[(it*4+2)*260 + tid] = v.z;
            sXT[(it*4+3)*260 + tid] = v.w;
        }
    }
    // preload B chunk k=0
    {
        const float4* p = (const float4*)W2b;
        #pragma unroll
        for (int j = 0; j < 4; ++j)
            ((float4*)sB[0])[tid + 256*j] = p[tid + 256*j];
    }
    __syncthreads();

    const int ty = tid >> 3;  const int tx = tid & 7;
    const int eb = ty * 8;    const int o0 = tx * 8;

    float ea_r[8][3];
    #pragma unroll
    for (int j = 0; j < 8; ++j)
        #pragma unroll
        for (int i = 0; i < 3; ++i) ea_r[j][i] = sea[(eb + j) * 4 + i];

    float C[8][8];
    #pragma unroll
    for (int j = 0; j < 8; ++j)
        #pragma unroll
        for (int l = 0; l < 8; ++l) C[j][l] = 0.f;

    int cur = 0;
    for (int k = 0; k <= 64; ++k) {
        // prefetch next B chunk into registers (chunk 64 = b2b bias block)
        float4 nx0, nx1, nx2, nx3;
        if (k < 64) {
            const float4* p = (k == 63) ? (const float4*)b2b
                                        : (const float4*)(W2b + (size_t)(k+1) * 4096);
            nx0 = p[tid]; nx1 = p[tid+256]; nx2 = p[tid+512]; nx3 = p[tid+768];
        }
        // h2a on the fly (scale for this k); k==64 -> bias row, scale 1
        float hh[8];
        if (k == 64) {
            #pragma unroll
            for (int j = 0; j < 8; ++j) hh[j] = 1.f;
        } else {
            #pragma unroll
            for (int j = 0; j < 8; ++j) {
                float h = sb2a[k] + ea_r[j][0]*sW2a[k] + ea_r[j][1]*sW2a[64+k] + ea_r[j][2]*sW2a[128+k];
                hh[j] = fmaxf(h, 0.f);
            }
        }
        const float* Bc = sB[cur];
        #pragma unroll 8
        for (int i = 0; i < 64; ++i) {
            float4 b0 = *(const float4*)&Bc[i*64 + o0];
            float4 b1 = *(const float4*)&Bc[i*64 + o0 + 4];
            float4 xa = *(const float4*)&sXT[i*260 + eb];
            float4 xb = *(const float4*)&sXT[i*260 + eb + 4];
            float a[8];
            a[0]=hh[0]*xa.x; a[1]=hh[1]*xa.y; a[2]=hh[2]*xa.z; a[3]=hh[3]*xa.w;
            a[4]=hh[4]*xb.x; a[5]=hh[5]*xb.y; a[6]=hh[6]*xb.z; a[7]=hh[7]*xb.w;
            #pragma unroll
            for (int j = 0; j < 8; ++j) { FMA8(C[j], a[j], b0, b1); }
        }
        if (k < 64) {
            float4* q = (float4*)sB[cur ^ 1];
            q[tid]=nx0; q[tid+256]=nx1; q[tid+512]=nx2; q[tid+768]=nx3;
        }
        cur ^= 1;
        __syncthreads();
    }
    #pragma unroll
    for (int j = 0; j < 8; ++j) {
        float* p = sum2 + (long)sdst[eb + j] * 64 + o0;
        #pragma unroll
        for (int l = 0; l < 8; ++l) atomicAdd(p + l, C[j][l]);
    }
}

// ---------------- layer-2 node update + FC, fused ----------------
__global__ __launch_bounds__(256, 2) void k4_final(
    const float* __restrict__ sum2, const float* __restrict__ cnt,
    const float* __restrict__ h1,
    const float* __restrict__ root2, const float* __restrict__ bias2,
    const float* __restrict__ Wf, const float* __restrict__ bf,
    float* __restrict__ out)
{
    __shared__ float sh1[32 * 65];
    __shared__ float sh2[32 * 65];
    __shared__ float sR[64 * 64];     // root2
    __shared__ float sW[64 * 128];    // Wf
    __shared__ float sb2[64];
    __shared__ float sbf[128];
    __shared__ float sinv[32];
    const int tid = threadIdx.x;
    const int n0 = blockIdx.x * 32;

    for (int u = tid; u < 64*64/4; u += 256) ((float4*)sR)[u] = ((const float4*)root2)[u];
    for (int u = tid; u < 64*128/4; u += 256) ((float4*)sW)[u] = ((const float4*)Wf)[u];
    if (tid < 64)  sb2[tid] = bias2[tid];
    if (tid < 128) sbf[tid] = bf[tid];
    if (tid < 32)  sinv[tid] = 1.f / fmaxf(cnt[n0 + tid], 1.f);
    for (int u = tid; u < 32 * 16; u += 256) {
        int n = u >> 4, i4 = (u & 15) * 4;
        float4 v = *(const float4*)&h1[(long)(n0 + n) * 64 + i4];
        sh1[n*65+i4] = v.x; sh1[n*65+i4+1] = v.y; sh1[n*65+i4+2] = v.z; sh1[n*65+i4+3] = v.w;
    }
    __syncthreads();

    // phase A: h2 = elu(sum2/cnt + h1@root2 + bias2)
    {
        const int tn = tid >> 4;       // 16 groups, 2 nodes each
        const int o0 = (tid & 15) * 4;
        float acc[2][4];
        #pragma unroll
        for (int j = 0; j < 2; ++j) {
            int n = tn * 2 + j;
            float inv = sinv[n];
            float4 s = *(const float4*)&sum2[(long)(n0 + n) * 64 + o0];
            acc[j][0] = s.x*inv + sb2[o0+0];
            acc[j][1] = s.y*inv + sb2[o0+1];
            acc[j][2] = s.z*inv + sb2[o0+2];
            acc[j][3] = s.w*inv + sb2[o0+3];
        }
        #pragma unroll 8
        for (int k = 0; k < 64; ++k) {
            float4 r = *(const float4*)&sR[k*64 + o0];
            float h0 = sh1[(tn*2)*65 + k];
            float h1v = sh1[(tn*2+1)*65 + k];
            acc[0][0] += h0*r.x; acc[0][1] += h0*r.y; acc[0][2] += h0*r.z; acc[0][3] += h0*r.w;
            acc[1][0] += h1v*r.x; acc[1][1] += h1v*r.y; acc[1][2] += h1v*r.z; acc[1][3] += h1v*r.w;
        }
        #pragma unroll
        for (int j = 0; j < 2; ++j) {
            int n = tn * 2 + j;
            #pragma unroll
            for (int l = 0; l < 4; ++l) sh2[n*65 + o0 + l] = elu_f(acc[j][l]);
        }
    }
    __syncthreads();

    // phase B: out = elu(h2 @ Wf + bf)
    {
        const int tn = tid >> 4;
        const int c0 = (tid & 15) * 8;
        float acc[2][8];
        #pragma unroll
        for (int j = 0; j < 2; ++j)
            #pragma unroll
            for (int l = 0; l < 8; ++l) acc[j][l] = sbf[c0 + l];
        #pragma unroll 8
        for (int k = 0; k < 64; ++k) {
            float4 w0 = *(const float4*)&sW[k*128 + c0];
            float4 w1 = *(const float4*)&sW[k*128 + c0 + 4];
            float h0 = sh2[(tn*2)*65 + k];
            float h1v = sh2[(tn*2+1)*65 + k];
            FMA8(acc[0], h0, w0, w1);
            FMA8(acc[1], h1v, w0, w1);
        }
        #pragma unroll
        for (int j = 0; j < 2; ++j) {
            long n = n0 + tn * 2 + j;
            float4 oA, oB;
            oA.x = elu_f(acc[j][0]); oA.y = elu_f(acc[j][1]); oA.z = elu_f(acc[j][2]); oA.w = elu_f(acc[j][3]);
            oB.x = elu_f(acc[j][4]); oB.y = elu_f(acc[j][5]); oB.z = elu_f(acc[j][6]); oB.w = elu_f(acc[j][7]);
            *(float4*)&out[n*128 + c0]     = oA;
            *(float4*)&out[n*128 + c0 + 4] = oB;
        }
    }
}

extern "C" void kernel_launch(void* const* d_in, const int* in_sizes, int n_in,
                              void* d_out, int out_size, void* d_ws, size_t ws_size,
                              hipStream_t stream)
{
    const float* x     = (const float*)d_in[0];
    const int*   ei    = (const int*)d_in[1];
    const float* ea    = (const float*)d_in[2];
    const float* W1a   = (const float*)d_in[3];
    const float* b1a   = (const float*)d_in[4];
    const float* W1b   = (const float*)d_in[5];
    const float* b1b   = (const float*)d_in[6];
    const float* root1 = (const float*)d_in[7];
    const float* bias1 = (const float*)d_in[8];
    const float* W2a   = (const float*)d_in[9];
    const float* b2a   = (const float*)d_in[10];
    const float* W2b   = (const float*)d_in[11];
    const float* b2b   = (const float*)d_in[12];
    const float* root2 = (const float*)d_in[13];
    const float* bias2 = (const float*)d_in[14];
    const float* Wf    = (const float*)d_in[15];
    const float* bf    = (const float*)d_in[16];
    float* out = (float*)d_out;

    float* ws   = (float*)d_ws;
    float* sum1 = ws;                                   // NN*64
    float* cnt  = ws + 2097152;                         // NN
    float* sum2 = ws + 2097152 + 32768;                 // NN*64
    float* h1   = ws + 2097152 + 32768 + 2097152;       // NN*64
    // total ws use: 25.3 MB

    // zero sum1 | cnt | sum2 (contiguous prefix)
    hipMemsetAsync(d_ws, 0, (size_t)(2097152 + 32768 + 2097152) * sizeof(float), stream);

    k_cnt   <<<NE/256,        256, 0, stream>>>(ei, cnt);
    k1_conv1<<<NE/256,        256, 0, stream>>>(x, ei, ea, W1a, b1a, W1b, b1b, sum1);
    k2_node1<<<NN*64/256,     256, 0, stream>>>(sum1, cnt, x, root1, bias1, h1);
    k3_conv2<<<NE/256,        256, 0, stream>>>(h1, ei, ea, W2a, b2a, W2b, b2b, sum2);
    k4_final<<<NN/32,         256, 0, stream>>>(sum2, cnt, h1, root2, bias2, Wf, bf, out);
}

// Round 3
// 387.276 us; speedup vs baseline: 2.1836x; 2.1836x over previous
//
#include <hip/hip_runtime.h>
#include <math.h>

#define NN 32768
#define NE 65536

typedef __attribute__((ext_vector_type(8))) short bf16x8;
typedef __attribute__((ext_vector_type(4))) float f32x4;

__device__ __forceinline__ float elu_f(float v) {
    return v > 0.f ? v : (expf(v) - 1.f);
}
__device__ __forceinline__ unsigned short bf16_rn(float f) {
    unsigned u = __float_as_uint(f);
    return (unsigned short)((u + 0x7FFFu + ((u >> 16) & 1u)) >> 16);
}
__device__ __forceinline__ float bf16_to_f(unsigned short h) {
    return __uint_as_float(((unsigned)h) << 16);
}

#define FMA8(Cj, aj, b0, b1) \
    Cj[0] += (aj)*(b0).x; Cj[1] += (aj)*(b0).y; Cj[2] += (aj)*(b0).z; Cj[3] += (aj)*(b0).w; \
    Cj[4] += (aj)*(b1).x; Cj[5] += (aj)*(b1).y; Cj[6] += (aj)*(b1).z; Cj[7] += (aj)*(b1).w;

// ---------------- count incoming edges per node ----------------
__global__ void k_cnt(const int* __restrict__ ei, float* __restrict__ cnt) {
    int e = blockIdx.x * 256 + threadIdx.x;
    if (e < NE) atomicAdd(&cnt[ei[NE + e]], 1.f);
}

// ---------------- prep: split W2b into bf16 hi/lo, transposed [i][o][k] with k-row padded to 72 ----------------
__global__ void k_prep(const float* __restrict__ W2b, short* __restrict__ BT) {
    int idx = blockIdx.x * 256 + threadIdx.x;   // 262144 = 4096 cols * 64 k
    int col = idx >> 6;        // i*64+o
    int k   = idx & 63;
    float f = W2b[(size_t)k * 4096 + col];
    unsigned short hi = bf16_rn(f);
    unsigned short lo = bf16_rn(f - bf16_to_f(hi));
    int i = col >> 6, o = col & 63;
    size_t base = (size_t)i * 9216;            // per-i: 4608 hi shorts + 4608 lo shorts
    BT[base + o * 72 + k]        = (short)hi;
    BT[base + 4608 + o * 72 + k] = (short)lo;
}

// ---------------- layer-1 edge messages (NNConv1) ----------------
__global__ __launch_bounds__(256, 2) void k1_conv1(
    const float* __restrict__ x, const int* __restrict__ ei,
    const float* __restrict__ eatt,
    const float* __restrict__ W1a, const float* __restrict__ b1a,
    const float* __restrict__ W1b, const float* __restrict__ b1b,
    float* __restrict__ sum1)
{
    __shared__ float sW1b[64 * 192];   // 48 KB
    __shared__ float sb1b[192];
    __shared__ float sW1a[192];
    __shared__ float sb1a[64];
    __shared__ float sxs[256 * 4];
    __shared__ float sea[256 * 4];
    __shared__ int   sdst[256];
    const int tid = threadIdx.x;
    const int e0 = blockIdx.x * 256;

    for (int u = tid; u < 64 * 192 / 4; u += 256)
        ((float4*)sW1b)[u] = ((const float4*)W1b)[u];
    if (tid < 192) { sW1a[tid] = W1a[tid]; sb1b[tid] = b1b[tid]; }
    if (tid < 64)  sb1a[tid] = b1a[tid];
    {
        int e = e0 + tid;
        int s = ei[e];
        sdst[tid] = ei[NE + e];
        sxs[tid*4+0] = x[s*3+0];
        sxs[tid*4+1] = x[s*3+1];
        sxs[tid*4+2] = x[s*3+2];
        sea[tid*4+0] = eatt[e*3+0];
        sea[tid*4+1] = eatt[e*3+1];
        sea[tid*4+2] = eatt[e*3+2];
    }
    __syncthreads();

    const int ty = tid >> 3;
    const int tx = tid & 7;
    const int eb = ty * 8;
    const int o0 = tx * 8;

    float xs_r[8][3], ea_r[8][3];
    #pragma unroll
    for (int j = 0; j < 8; ++j)
        #pragma unroll
        for (int i = 0; i < 3; ++i) {
            xs_r[j][i] = sxs[(eb + j) * 4 + i];
            ea_r[j][i] = sea[(eb + j) * 4 + i];
        }

    float C[8][8];
    #pragma unroll
    for (int j = 0; j < 8; ++j)
        #pragma unroll
        for (int l = 0; l < 8; ++l) C[j][l] = 0.f;

    for (int k = 0; k < 64; ++k) {
        float hh[8];
        #pragma unroll
        for (int j = 0; j < 8; ++j) {
            float h = sb1a[k] + ea_r[j][0]*sW1a[k] + ea_r[j][1]*sW1a[64+k] + ea_r[j][2]*sW1a[128+k];
            hh[j] = fmaxf(h, 0.f);
        }
        #pragma unroll
        for (int i = 0; i < 3; ++i) {
            const float4* wp = (const float4*)&sW1b[k*192 + i*64 + o0];
            float4 w0 = wp[0], w1 = wp[1];
            float a[8];
            #pragma unroll
            for (int j = 0; j < 8; ++j) a[j] = hh[j] * xs_r[j][i];
            #pragma unroll
            for (int j = 0; j < 8; ++j) { FMA8(C[j], a[j], w0, w1); }
        }
    }
    #pragma unroll
    for (int i = 0; i < 3; ++i) {
        const float4* wp = (const float4*)&sb1b[i*64 + o0];
        float4 w0 = wp[0], w1 = wp[1];
        #pragma unroll
        for (int j = 0; j < 8; ++j) {
            float a = xs_r[j][i];
            FMA8(C[j], a, w0, w1);
        }
    }
    #pragma unroll
    for (int j = 0; j < 8; ++j) {
        float* p = sum1 + (long)sdst[eb + j] * 64 + o0;
        #pragma unroll
        for (int l = 0; l < 8; ++l) atomicAdd(p + l, C[j][l]);
    }
}

// ---------------- layer-1 node update ----------------
__global__ void k2_node1(const float* __restrict__ sum1, const float* __restrict__ cnt,
                         const float* __restrict__ x, const float* __restrict__ root1,
                         const float* __restrict__ bias1, float* __restrict__ h1)
{
    int g = blockIdx.x * 256 + threadIdx.x;
    int n = g >> 6, o = g & 63;
    float inv = 1.f / fmaxf(cnt[n], 1.f);
    float v = sum1[g] * inv + bias1[o];
    v += x[n*3+0]*root1[o] + x[n*3+1]*root1[64+o] + x[n*3+2]*root1[128+o];
    h1[g] = elu_f(v);
}

// ---------------- layer-2 edge messages: MFMA split-precision ----------------
// msg[e,o] = sum_i v[e,i] * ( u[e,:] @ W2b[:, i*64+o] + b2b[i*64+o] )
// u = relu(ea@W2a+b2a) in registers as bf16 hi/lo A-fragments; B streamed hi/lo per i.
// 256 edges/block, 4 waves; wave owns 64 edges x 64 o (4 row-tiles x 4 o-tiles of 16x16).
__global__ __launch_bounds__(256, 1) void k3_mfma(
    const float* __restrict__ h1, const int* __restrict__ ei,
    const float* __restrict__ eatt,
    const float* __restrict__ W2a, const float* __restrict__ b2a,
    const short* __restrict__ BT, const float* __restrict__ b2b,
    float* __restrict__ sum2)
{
    __shared__ __align__(16) float sX[17408];       // u: [256][68] fp32, then vT: [64][260] fp32
    __shared__ __align__(16) short sB[2][9216];     // dbuf: hi[64*72] | lo[64*72]
    __shared__ float sbb[4096];                     // b2b
    __shared__ float sw2a[192];
    __shared__ float sb2a2[64];
    __shared__ int   sdst[256];

    const int tid = threadIdx.x;
    const int e0  = blockIdx.x * 256;
    const int wid = tid >> 6;
    const int lane = tid & 63;
    const int l15 = lane & 15, lhi = lane >> 4;

    if (tid < 192) sw2a[tid] = W2a[tid];
    if (tid < 64)  sb2a2[tid] = b2a[tid];
    for (int u = tid; u < 1024; u += 256) ((float4*)sbb)[u] = ((const float4*)b2b)[u];
    sdst[tid] = ei[NE + e0 + tid];
    const int esrc = ei[e0 + tid];
    float ea0 = eatt[(e0+tid)*3+0], ea1 = eatt[(e0+tid)*3+1], ea2 = eatt[(e0+tid)*3+2];
    __syncthreads();

    // u[e][k] into sX, stride 68
    for (int k = 0; k < 64; ++k) {
        float h = sb2a2[k] + ea0*sw2a[k] + ea1*sw2a[64+k] + ea2*sw2a[128+k];
        sX[tid*68 + k] = fmaxf(h, 0.f);
    }
    __syncthreads();

    // A-fragments: row = l15 (within 16-tile), k = kc*32 + lhi*8 + j
    bf16x8 ah[4][2], al[4][2];
    #pragma unroll
    for (int rt = 0; rt < 4; ++rt)
        #pragma unroll
        for (int kc = 0; kc < 2; ++kc) {
            const float* p = &sX[(wid*64 + rt*16 + l15)*68 + kc*32 + lhi*8];
            bf16x8 H, L;
            #pragma unroll
            for (int j = 0; j < 8; ++j) {
                float f = p[j];
                unsigned short hh = bf16_rn(f);
                unsigned short ll = bf16_rn(f - bf16_to_f(hh));
                H[j] = (short)hh; L[j] = (short)ll;
            }
            ah[rt][kc] = H; al[rt][kc] = L;
        }
    __syncthreads();

    // vT[i][e] gather (overwrites u region), stride 260
    {
        const float* row = h1 + (size_t)esrc * 64;
        #pragma unroll
        for (int it = 0; it < 16; ++it) {
            float4 vv = *(const float4*)(row + it*4);
            sX[(it*4+0)*260 + tid] = vv.x;
            sX[(it*4+1)*260 + tid] = vv.y;
            sX[(it*4+2)*260 + tid] = vv.z;
            sX[(it*4+3)*260 + tid] = vv.w;
        }
    }
    // stage B_0 (18432 B = 4608 u32)
    {
        const unsigned* src = (const unsigned*)BT;
        unsigned* dst = (unsigned*)sB[0];
        #pragma unroll
        for (int j = 0; j < 18; ++j) dst[tid + 256*j] = src[tid + 256*j];
    }
    __syncthreads();

    f32x4 acc[4][4];
    #pragma unroll
    for (int rt = 0; rt < 4; ++rt)
        #pragma unroll
        for (int ot = 0; ot < 4; ++ot) { acc[rt][ot][0]=0.f; acc[rt][ot][1]=0.f; acc[rt][ot][2]=0.f; acc[rt][ot][3]=0.f; }

    int cur = 0;
    for (int i = 0; i < 64; ++i) {
        // prefetch next B chunk to regs
        unsigned pf[18];
        if (i < 63) {
            const unsigned* src = (const unsigned*)(BT + (size_t)(i+1) * 9216);
            #pragma unroll
            for (int j = 0; j < 18; ++j) pf[j] = src[tid + 256*j];
        }
        // v scalars for this i: rows = wid*64 + rt*16 + lhi*4 + r
        float vv[4][4];
        #pragma unroll
        for (int rt = 0; rt < 4; ++rt) {
            f32x4 t4 = *(const f32x4*)&sX[i*260 + wid*64 + rt*16 + lhi*4];
            vv[rt][0]=t4[0]; vv[rt][1]=t4[1]; vv[rt][2]=t4[2]; vv[rt][3]=t4[3];
        }
        const short* Bh = &sB[cur][0];
        const short* Bl = &sB[cur][4608];
        #pragma unroll
        for (int ot = 0; ot < 4; ++ot) {
            const int ob = (ot*16 + l15)*72 + lhi*8;
            bf16x8 bh0 = *(const bf16x8*)&Bh[ob];
            bf16x8 bh1 = *(const bf16x8*)&Bh[ob + 32];
            bf16x8 bl0 = *(const bf16x8*)&Bl[ob];
            bf16x8 bl1 = *(const bf16x8*)&Bl[ob + 32];
            float bb = sbb[i*64 + ot*16 + l15];
            #pragma unroll
            for (int rt = 0; rt < 4; ++rt) {
                f32x4 t = {0.f, 0.f, 0.f, 0.f};
                t = __builtin_amdgcn_mfma_f32_16x16x32_bf16(ah[rt][0], bh0, t, 0, 0, 0);
                t = __builtin_amdgcn_mfma_f32_16x16x32_bf16(al[rt][0], bh0, t, 0, 0, 0);
                t = __builtin_amdgcn_mfma_f32_16x16x32_bf16(ah[rt][0], bl0, t, 0, 0, 0);
                t = __builtin_amdgcn_mfma_f32_16x16x32_bf16(ah[rt][1], bh1, t, 0, 0, 0);
                t = __builtin_amdgcn_mfma_f32_16x16x32_bf16(al[rt][1], bh1, t, 0, 0, 0);
                t = __builtin_amdgcn_mfma_f32_16x16x32_bf16(ah[rt][1], bl1, t, 0, 0, 0);
                #pragma unroll
                for (int r = 0; r < 4; ++r)
                    acc[rt][ot][r] += vv[rt][r] * (t[r] + bb);
            }
        }
        if (i < 63) {
            unsigned* dst = (unsigned*)sB[cur ^ 1];
            #pragma unroll
            for (int j = 0; j < 18; ++j) dst[tid + 256*j] = pf[j];
            cur ^= 1;
        }
        __syncthreads();
    }

    // scatter: D-layout row = lhi*4 + r, col = l15
    #pragma unroll
    for (int rt = 0; rt < 4; ++rt) {
        const int rowb = wid*64 + rt*16 + lhi*4;
        int dd[4];
        #pragma unroll
        for (int r = 0; r < 4; ++r) dd[r] = sdst[rowb + r];
        #pragma unroll
        for (int ot = 0; ot < 4; ++ot) {
            const int o = ot*16 + l15;
            #pragma unroll
            for (int r = 0; r < 4; ++r)
                atomicAdd(&sum2[(size_t)dd[r]*64 + o], acc[rt][ot][r]);
        }
    }
}

// ---------------- layer-2 node update + FC, fused ----------------
__global__ __launch_bounds__(256, 2) void k4_final(
    const float* __restrict__ sum2, const float* __restrict__ cnt,
    const float* __restrict__ h1,
    const float* __restrict__ root2, const float* __restrict__ bias2,
    const float* __restrict__ Wf, const float* __restrict__ bf,
    float* __restrict__ out)
{
    __shared__ float sh1[32 * 65];
    __shared__ float sh2[32 * 65];
    __shared__ float sR[64 * 64];
    __shared__ float sW[64 * 128];
    __shared__ float sb2[64];
    __shared__ float sbf[128];
    __shared__ float sinv[32];
    const int tid = threadIdx.x;
    const int n0 = blockIdx.x * 32;

    for (int u = tid; u < 64*64/4; u += 256) ((float4*)sR)[u] = ((const float4*)root2)[u];
    for (int u = tid; u < 64*128/4; u += 256) ((float4*)sW)[u] = ((const float4*)Wf)[u];
    if (tid < 64)  sb2[tid] = bias2[tid];
    if (tid < 128) sbf[tid] = bf[tid];
    if (tid < 32)  sinv[tid] = 1.f / fmaxf(cnt[n0 + tid], 1.f);
    for (int u = tid; u < 32 * 16; u += 256) {
        int n = u >> 4, i4 = (u & 15) * 4;
        float4 v = *(const float4*)&h1[(long)(n0 + n) * 64 + i4];
        sh1[n*65+i4] = v.x; sh1[n*65+i4+1] = v.y; sh1[n*65+i4+2] = v.z; sh1[n*65+i4+3] = v.w;
    }
    __syncthreads();

    {
        const int tn = tid >> 4;
        const int o0 = (tid & 15) * 4;
        float acc[2][4];
        #pragma unroll
        for (int j = 0; j < 2; ++j) {
            int n = tn * 2 + j;
            float inv = sinv[n];
            float4 s = *(const float4*)&sum2[(long)(n0 + n) * 64 + o0];
            acc[j][0] = s.x*inv + sb2[o0+0];
            acc[j][1] = s.y*inv + sb2[o0+1];
            acc[j][2] = s.z*inv + sb2[o0+2];
            acc[j][3] = s.w*inv + sb2[o0+3];
        }
        #pragma unroll 8
        for (int k = 0; k < 64; ++k) {
            float4 r = *(const float4*)&sR[k*64 + o0];
            float h0 = sh1[(tn*2)*65 + k];
            float h1v = sh1[(tn*2+1)*65 + k];
            acc[0][0] += h0*r.x; acc[0][1] += h0*r.y; acc[0][2] += h0*r.z; acc[0][3] += h0*r.w;
            acc[1][0] += h1v*r.x; acc[1][1] += h1v*r.y; acc[1][2] += h1v*r.z; acc[1][3] += h1v*r.w;
        }
        #pragma unroll
        for (int j = 0; j < 2; ++j) {
            int n = tn * 2 + j;
            #pragma unroll
            for (int l = 0; l < 4; ++l) sh2[n*65 + o0 + l] = elu_f(acc[j][l]);
        }
    }
    __syncthreads();

    {
        const int tn = tid >> 4;
        const int c0 = (tid & 15) * 8;
        float acc[2][8];
        #pragma unroll
        for (int j = 0; j < 2; ++j)
            #pragma unroll
            for (int l = 0; l < 8; ++l) acc[j][l] = sbf[c0 + l];
        #pragma unroll 8
        for (int k = 0; k < 64; ++k) {
            float4 w0 = *(const float4*)&sW[k*128 + c0];
            float4 w1 = *(const float4*)&sW[k*128 + c0 + 4];
            float h0 = sh2[(tn*2)*65 + k];
            float h1v = sh2[(tn*2+1)*65 + k];
            FMA8(acc[0], h0, w0, w1);
            FMA8(acc[1], h1v, w0, w1);
        }
        #pragma unroll
        for (int j = 0; j < 2; ++j) {
            long n = n0 + tn * 2 + j;
            float4 oA, oB;
            oA.x = elu_f(acc[j][0]); oA.y = elu_f(acc[j][1]); oA.z = elu_f(acc[j][2]); oA.w = elu_f(acc[j][3]);
            oB.x = elu_f(acc[j][4]); oB.y = elu_f(acc[j][5]); oB.z = elu_f(acc[j][6]); oB.w = elu_f(acc[j][7]);
            *(float4*)&out[n*128 + c0]     = oA;
            *(float4*)&out[n*128 + c0 + 4] = oB;
        }
    }
}

extern "C" void kernel_launch(void* const* d_in, const int* in_sizes, int n_in,
                              void* d_out, int out_size, void* d_ws, size_t ws_size,
                              hipStream_t stream)
{
    const float* x     = (const float*)d_in[0];
    const int*   ei    = (const int*)d_in[1];
    const float* ea    = (const float*)d_in[2];
    const float* W1a   = (const float*)d_in[3];
    const float* b1a   = (const float*)d_in[4];
    const float* W1b   = (const float*)d_in[5];
    const float* b1b   = (const float*)d_in[6];
    const float* root1 = (const float*)d_in[7];
    const float* bias1 = (const float*)d_in[8];
    const float* W2a   = (const float*)d_in[9];
    const float* b2a   = (const float*)d_in[10];
    const float* W2b   = (const float*)d_in[11];
    const float* b2b   = (const float*)d_in[12];
    const float* root2 = (const float*)d_in[13];
    const float* bias2 = (const float*)d_in[14];
    const float* Wf    = (const float*)d_in[15];
    const float* bf    = (const float*)d_in[16];
    float* out = (float*)d_out;

    float* ws   = (float*)d_ws;
    float* sum1 = ws;                                   // NN*64
    float* cnt  = ws + 2097152;                         // NN
    float* sum2 = ws + 2097152 + 32768;                 // NN*64
    float* h1   = ws + 2097152 + 32768 + 2097152;       // NN*64
    short* BT   = (short*)(ws + 2097152 + 32768 + 2097152 + 2097152);  // 589824 shorts

    hipMemsetAsync(d_ws, 0, (size_t)(2097152 + 32768 + 2097152) * sizeof(float), stream);

    k_prep  <<<1024,      256, 0, stream>>>(W2b, BT);
    k_cnt   <<<NE/256,    256, 0, stream>>>(ei, cnt);
    k1_conv1<<<NE/256,    256, 0, stream>>>(x, ei, ea, W1a, b1a, W1b, b1b, sum1);
    k2_node1<<<NN*64/256, 256, 0, stream>>>(sum1, cnt, x, root1, bias1, h1);
    k3_mfma <<<NE/256,    256, 0, stream>>>(h1, ei, ea, W2a, b2a, BT, b2b, sum2);
    k4_final<<<NN/32,     256, 0, stream>>>(sum2, cnt, h1, root2, bias2, Wf, bf, out);
}

// Round 4
// 290.991 us; speedup vs baseline: 2.9062x; 1.3309x over previous
//
#include <hip/hip_runtime.h>
#include <math.h>

#define NN 32768
#define NE 65536

typedef __attribute__((ext_vector_type(8))) short bf16x8;
typedef __attribute__((ext_vector_type(4))) float f32x4;

__device__ __forceinline__ float elu_f(float v) {
    return v > 0.f ? v : (expf(v) - 1.f);
}
__device__ __forceinline__ unsigned short bf16_rn(float f) {
    unsigned u = __float_as_uint(f);
    return (unsigned short)((u + 0x7FFFu + ((u >> 16) & 1u)) >> 16);
}
__device__ __forceinline__ float bf16_to_f(unsigned short h) {
    return __uint_as_float(((unsigned)h) << 16);
}

#define FMA8(Cj, aj, b0, b1) \
    Cj[0] += (aj)*(b0).x; Cj[1] += (aj)*(b0).y; Cj[2] += (aj)*(b0).z; Cj[3] += (aj)*(b0).w; \
    Cj[4] += (aj)*(b1).x; Cj[5] += (aj)*(b1).y; Cj[6] += (aj)*(b1).z; Cj[7] += (aj)*(b1).w;

// ---------------- CSR build: histogram, scan, fill ----------------
__global__ void k_hist(const int* __restrict__ ei, int* __restrict__ cnt) {
    int e = blockIdx.x * 256 + threadIdx.x;
    if (e < NE) atomicAdd(&cnt[ei[NE + e]], 1);
}

__global__ __launch_bounds__(1024) void k_scan(const int* __restrict__ cnt,
                                               int* __restrict__ start,
                                               int* __restrict__ cursor) {
    __shared__ int wtot[16];
    const int t = threadIdx.x;
    const int lane = t & 63, wave = t >> 6;
    int local[32];
    const int base = t * 32;
    int s = 0;
    #pragma unroll
    for (int j = 0; j < 32; ++j) { local[j] = s; s += cnt[base + j]; }
    const int tot = s;
    int sc = tot;
    #pragma unroll
    for (int off = 1; off < 64; off <<= 1) {
        int v = __shfl_up(sc, off, 64);
        if (lane >= off) sc += v;
    }
    if (lane == 63) wtot[wave] = sc;
    __syncthreads();
    if (t == 0) {
        int run = 0;
        #pragma unroll
        for (int w = 0; w < 16; ++w) { int v = wtot[w]; wtot[w] = run; run += v; }
    }
    __syncthreads();
    const int tbase = wtot[wave] + (sc - tot);
    #pragma unroll
    for (int j = 0; j < 32; ++j) {
        int v = tbase + local[j];
        start[base + j] = v;
        cursor[base + j] = v;
    }
}

__global__ void k_fill(const int* __restrict__ ei, int* __restrict__ cursor,
                       int* __restrict__ perm) {
    int e = blockIdx.x * 256 + threadIdx.x;
    if (e < NE) {
        int d = ei[NE + e];
        int pos = atomicAdd(&cursor[d], 1);
        perm[pos] = e;
    }
}

// ---------------- prep: split W2b into bf16 hi/lo, transposed [i][o][k], k-row padded to 72 ----------------
__global__ void k_prep(const float* __restrict__ W2b, short* __restrict__ BT) {
    int idx = blockIdx.x * 256 + threadIdx.x;   // 262144
    int col = idx >> 6;
    int k   = idx & 63;
    float f = W2b[(size_t)k * 4096 + col];
    unsigned short hi = bf16_rn(f);
    unsigned short lo = bf16_rn(f - bf16_to_f(hi));
    int i = col >> 6, o = col & 63;
    size_t base = (size_t)i * 9216;
    BT[base + o * 72 + k]        = (short)hi;
    BT[base + 4608 + o * 72 + k] = (short)lo;
}

// ---------------- layer-1 edge messages, sorted order, plain stores ----------------
__global__ __launch_bounds__(256, 2) void k1_conv1(
    const float* __restrict__ x, const int* __restrict__ ei,
    const float* __restrict__ eatt, const int* __restrict__ perm,
    const float* __restrict__ W1a, const float* __restrict__ b1a,
    const float* __restrict__ W1b, const float* __restrict__ b1b,
    float* __restrict__ msg1)
{
    __shared__ float sW1b[64 * 192];   // 48 KB
    __shared__ float sb1b[192];
    __shared__ float sW1a[192];
    __shared__ float sb1a[64];
    __shared__ float sxs[256 * 4];
    __shared__ float sea[256 * 4];
    const int tid = threadIdx.x;
    const int e0 = blockIdx.x * 256;

    for (int u = tid; u < 64 * 192 / 4; u += 256)
        ((float4*)sW1b)[u] = ((const float4*)W1b)[u];
    if (tid < 192) { sW1a[tid] = W1a[tid]; sb1b[tid] = b1b[tid]; }
    if (tid < 64)  sb1a[tid] = b1a[tid];
    {
        int pe = perm[e0 + tid];
        int s = ei[pe];
        sxs[tid*4+0] = x[s*3+0];
        sxs[tid*4+1] = x[s*3+1];
        sxs[tid*4+2] = x[s*3+2];
        sea[tid*4+0] = eatt[pe*3+0];
        sea[tid*4+1] = eatt[pe*3+1];
        sea[tid*4+2] = eatt[pe*3+2];
    }
    __syncthreads();

    const int ty = tid >> 3;
    const int tx = tid & 7;
    const int eb = ty * 8;
    const int o0 = tx * 8;

    float xs_r[8][3], ea_r[8][3];
    #pragma unroll
    for (int j = 0; j < 8; ++j)
        #pragma unroll
        for (int i = 0; i < 3; ++i) {
            xs_r[j][i] = sxs[(eb + j) * 4 + i];
            ea_r[j][i] = sea[(eb + j) * 4 + i];
        }

    float C[8][8];
    #pragma unroll
    for (int j = 0; j < 8; ++j)
        #pragma unroll
        for (int l = 0; l < 8; ++l) C[j][l] = 0.f;

    for (int k = 0; k < 64; ++k) {
        float hh[8];
        #pragma unroll
        for (int j = 0; j < 8; ++j) {
            float h = sb1a[k] + ea_r[j][0]*sW1a[k] + ea_r[j][1]*sW1a[64+k] + ea_r[j][2]*sW1a[128+k];
            hh[j] = fmaxf(h, 0.f);
        }
        #pragma unroll
        for (int i = 0; i < 3; ++i) {
            const float4* wp = (const float4*)&sW1b[k*192 + i*64 + o0];
            float4 w0 = wp[0], w1 = wp[1];
            float a[8];
            #pragma unroll
            for (int j = 0; j < 8; ++j) a[j] = hh[j] * xs_r[j][i];
            #pragma unroll
            for (int j = 0; j < 8; ++j) { FMA8(C[j], a[j], w0, w1); }
        }
    }
    #pragma unroll
    for (int i = 0; i < 3; ++i) {
        const float4* wp = (const float4*)&sb1b[i*64 + o0];
        float4 w0 = wp[0], w1 = wp[1];
        #pragma unroll
        for (int j = 0; j < 8; ++j) {
            float a = xs_r[j][i];
            FMA8(C[j], a, w0, w1);
        }
    }
    #pragma unroll
    for (int j = 0; j < 8; ++j) {
        float* p = msg1 + (size_t)(e0 + eb + j) * 64 + o0;
        float4 v0 = { C[j][0], C[j][1], C[j][2], C[j][3] };
        float4 v1 = { C[j][4], C[j][5], C[j][6], C[j][7] };
        *(float4*)p       = v0;
        *(float4*)(p + 4) = v1;
    }
}

// ---------------- layer-1 node update: segmented sum ----------------
__global__ __launch_bounds__(256) void k2_node1(
    const float* __restrict__ msg1, const int* __restrict__ start,
    const int* __restrict__ cnt,
    const float* __restrict__ x, const float* __restrict__ root1,
    const float* __restrict__ bias1, float* __restrict__ h1)
{
    __shared__ float sR[192], sb[64];
    const int tid = threadIdx.x;
    if (tid < 192) sR[tid] = root1[tid];
    if (tid < 64)  sb[tid] = bias1[tid];
    __syncthreads();
    const int n = blockIdx.x * 64 + (tid >> 2);
    const int c = (tid & 3) * 16;
    const int st = start[n], num = cnt[n];
    float acc[16];
    #pragma unroll
    for (int l = 0; l < 16; ++l) acc[l] = 0.f;
    for (int d = 0; d < num; ++d) {
        const float* row = &msg1[(size_t)(st + d) * 64 + c];
        #pragma unroll
        for (int q = 0; q < 4; ++q) {
            float4 v = *(const float4*)(row + q * 4);
            acc[q*4+0] += v.x; acc[q*4+1] += v.y; acc[q*4+2] += v.z; acc[q*4+3] += v.w;
        }
    }
    const float inv = 1.f / fmaxf((float)num, 1.f);
    const float x0 = x[n*3+0], x1 = x[n*3+1], x2 = x[n*3+2];
    float* hp = &h1[(size_t)n * 64 + c];
    #pragma unroll
    for (int q = 0; q < 4; ++q) {
        float4 ov;
        float* o4 = (float*)&ov;
        #pragma unroll
        for (int l = 0; l < 4; ++l) {
            int o = c + q*4 + l;
            float v = acc[q*4+l] * inv + sb[o] + x0*sR[o] + x1*sR[64+o] + x2*sR[128+o];
            o4[l] = elu_f(v);
        }
        *(float4*)(hp + q*4) = ov;
    }
}

// ---------------- layer-2 edge messages: MFMA split-precision, sorted order ----------------
__global__ __launch_bounds__(256, 1) void k3_mfma(
    const float* __restrict__ h1, const int* __restrict__ ei,
    const float* __restrict__ eatt, const int* __restrict__ perm,
    const float* __restrict__ W2a, const float* __restrict__ b2a,
    const short* __restrict__ BT, const float* __restrict__ b2b,
    float* __restrict__ msg2)
{
    __shared__ __align__(16) float sX[17408];       // u: [256][68], then vT: [64][260]
    __shared__ __align__(16) short sB[2][9216];
    __shared__ float sbb[4096];
    __shared__ float sw2a[192];
    __shared__ float sb2a2[64];

    const int tid = threadIdx.x;
    const int e0  = blockIdx.x * 256;
    const int wid = tid >> 6;
    const int lane = tid & 63;
    const int l15 = lane & 15, lhi = lane >> 4;

    if (tid < 192) sw2a[tid] = W2a[tid];
    if (tid < 64)  sb2a2[tid] = b2a[tid];
    for (int u = tid; u < 1024; u += 256) ((float4*)sbb)[u] = ((const float4*)b2b)[u];
    const int pe = perm[e0 + tid];
    const int esrc = ei[pe];
    float ea0 = eatt[pe*3+0], ea1 = eatt[pe*3+1], ea2 = eatt[pe*3+2];
    __syncthreads();

    for (int k = 0; k < 64; ++k) {
        float h = sb2a2[k] + ea0*sw2a[k] + ea1*sw2a[64+k] + ea2*sw2a[128+k];
        sX[tid*68 + k] = fmaxf(h, 0.f);
    }
    __syncthreads();

    bf16x8 ah[4][2], al[4][2];
    #pragma unroll
    for (int rt = 0; rt < 4; ++rt)
        #pragma unroll
        for (int kc = 0; kc < 2; ++kc) {
            const float* p = &sX[(wid*64 + rt*16 + l15)*68 + kc*32 + lhi*8];
            bf16x8 H, L;
            #pragma unroll
            for (int j = 0; j < 8; ++j) {
                float f = p[j];
                unsigned short hh = bf16_rn(f);
                unsigned short ll = bf16_rn(f - bf16_to_f(hh));
                H[j] = (short)hh; L[j] = (short)ll;
            }
            ah[rt][kc] = H; al[rt][kc] = L;
        }
    __syncthreads();

    {
        const float* row = h1 + (size_t)esrc * 64;
        #pragma unroll
        for (int it = 0; it < 16; ++it) {
            float4 vv = *(const float4*)(row + it*4);
            sX[(it*4+0)*260 + tid] = vv.x;
            sX[(it*4+1)*260 + tid] = vv.y;
            sX[(it*4+2)*260 + tid] = vv.z;
            sX[(it*4+3)*260 + tid] = vv.w;
        }
    }
    {
        const unsigned* src = (const unsigned*)BT;
        unsigned* dst = (unsigned*)sB[0];
        #pragma unroll
        for (int j = 0; j < 18; ++j) dst[tid + 256*j] = src[tid + 256*j];
    }
    __syncthreads();

    f32x4 acc[4][4];
    #pragma unroll
    for (int rt = 0; rt < 4; ++rt)
        #pragma unroll
        for (int ot = 0; ot < 4; ++ot) { acc[rt][ot][0]=0.f; acc[rt][ot][1]=0.f; acc[rt][ot][2]=0.f; acc[rt][ot][3]=0.f; }

    int cur = 0;
    for (int i = 0; i < 64; ++i) {
        unsigned pf[18];
        if (i < 63) {
            const unsigned* src = (const unsigned*)(BT + (size_t)(i+1) * 9216);
            #pragma unroll
            for (int j = 0; j < 18; ++j) pf[j] = src[tid + 256*j];
        }
        float vv[4][4];
        #pragma unroll
        for (int rt = 0; rt < 4; ++rt) {
            f32x4 t4 = *(const f32x4*)&sX[i*260 + wid*64 + rt*16 + lhi*4];
            vv[rt][0]=t4[0]; vv[rt][1]=t4[1]; vv[rt][2]=t4[2]; vv[rt][3]=t4[3];
        }
        const short* Bh = &sB[cur][0];
        const short* Bl = &sB[cur][4608];
        #pragma unroll
        for (int ot = 0; ot < 4; ++ot) {
            const int ob = (ot*16 + l15)*72 + lhi*8;
            bf16x8 bh0 = *(const bf16x8*)&Bh[ob];
            bf16x8 bh1 = *(const bf16x8*)&Bh[ob + 32];
            bf16x8 bl0 = *(const bf16x8*)&Bl[ob];
            bf16x8 bl1 = *(const bf16x8*)&Bl[ob + 32];
            float bb = sbb[i*64 + ot*16 + l15];
            #pragma unroll
            for (int rt = 0; rt < 4; ++rt) {
                f32x4 t = {0.f, 0.f, 0.f, 0.f};
                t = __builtin_amdgcn_mfma_f32_16x16x32_bf16(ah[rt][0], bh0, t, 0, 0, 0);
                t = __builtin_amdgcn_mfma_f32_16x16x32_bf16(al[rt][0], bh0, t, 0, 0, 0);
                t = __builtin_amdgcn_mfma_f32_16x16x32_bf16(ah[rt][0], bl0, t, 0, 0, 0);
                t = __builtin_amdgcn_mfma_f32_16x16x32_bf16(ah[rt][1], bh1, t, 0, 0, 0);
                t = __builtin_amdgcn_mfma_f32_16x16x32_bf16(al[rt][1], bh1, t, 0, 0, 0);
                t = __builtin_amdgcn_mfma_f32_16x16x32_bf16(ah[rt][1], bl1, t, 0, 0, 0);
                #pragma unroll
                for (int r = 0; r < 4; ++r)
                    acc[rt][ot][r] += vv[rt][r] * (t[r] + bb);
            }
        }
        if (i < 63) {
            unsigned* dst = (unsigned*)sB[cur ^ 1];
            #pragma unroll
            for (int j = 0; j < 18; ++j) dst[tid + 256*j] = pf[j];
            cur ^= 1;
        }
        __syncthreads();
    }

    // store: D row = lhi*4 + r, col = l15; sorted row index = e0 + wid*64 + rt*16 + lhi*4 + r
    #pragma unroll
    for (int rt = 0; rt < 4; ++rt) {
        const int rowb = e0 + wid*64 + rt*16 + lhi*4;
        #pragma unroll
        for (int ot = 0; ot < 4; ++ot) {
            const int o = ot*16 + l15;
            #pragma unroll
            for (int r = 0; r < 4; ++r)
                msg2[(size_t)(rowb + r)*64 + o] = acc[rt][ot][r];
        }
    }
}

// ---------------- layer-2 node update + FC, fused, segmented sum ----------------
__global__ __launch_bounds__(256, 2) void k4_final(
    const float* __restrict__ msg2, const int* __restrict__ start,
    const int* __restrict__ cnt,
    const float* __restrict__ h1,
    const float* __restrict__ root2, const float* __restrict__ bias2,
    const float* __restrict__ Wf, const float* __restrict__ bf,
    float* __restrict__ out)
{
    __shared__ float sh1[32 * 65];
    __shared__ float sh2[32 * 65];
    __shared__ float sR[64 * 64];
    __shared__ float sW[64 * 128];
    __shared__ float sb2[64];
    __shared__ float sbf[128];
    __shared__ float sinv[32];
    __shared__ int   sstart[32];
    __shared__ int   scnt[32];
    const int tid = threadIdx.x;
    const int n0 = blockIdx.x * 32;

    for (int u = tid; u < 64*64/4; u += 256) ((float4*)sR)[u] = ((const float4*)root2)[u];
    for (int u = tid; u < 64*128/4; u += 256) ((float4*)sW)[u] = ((const float4*)Wf)[u];
    if (tid < 64)  sb2[tid] = bias2[tid];
    if (tid < 128) sbf[tid] = bf[tid];
    if (tid < 32) {
        int n = n0 + tid;
        int cc = cnt[n];
        sstart[tid] = start[n];
        scnt[tid] = cc;
        sinv[tid] = 1.f / fmaxf((float)cc, 1.f);
    }
    for (int u = tid; u < 32 * 16; u += 256) {
        int n = u >> 4, i4 = (u & 15) * 4;
        float4 v = *(const float4*)&h1[(size_t)(n0 + n) * 64 + i4];
        sh1[n*65+i4] = v.x; sh1[n*65+i4+1] = v.y; sh1[n*65+i4+2] = v.z; sh1[n*65+i4+3] = v.w;
    }
    __syncthreads();

    {
        const int tn = tid >> 4;
        const int o0 = (tid & 15) * 4;
        float acc[2][4];
        #pragma unroll
        for (int j = 0; j < 2; ++j) {
            int ln = tn * 2 + j;
            int st = sstart[ln], num = scnt[ln];
            float4 a = {0.f, 0.f, 0.f, 0.f};
            for (int d = 0; d < num; ++d) {
                float4 s = *(const float4*)&msg2[(size_t)(st + d) * 64 + o0];
                a.x += s.x; a.y += s.y; a.z += s.z; a.w += s.w;
            }
            float inv = sinv[ln];
            acc[j][0] = a.x*inv + sb2[o0+0];
            acc[j][1] = a.y*inv + sb2[o0+1];
            acc[j][2] = a.z*inv + sb2[o0+2];
            acc[j][3] = a.w*inv + sb2[o0+3];
        }
        #pragma unroll 8
        for (int k = 0; k < 64; ++k) {
            float4 r = *(const float4*)&sR[k*64 + o0];
            float h0 = sh1[(tn*2)*65 + k];
            float h1v = sh1[(tn*2+1)*65 + k];
            acc[0][0] += h0*r.x; acc[0][1] += h0*r.y; acc[0][2] += h0*r.z; acc[0][3] += h0*r.w;
            acc[1][0] += h1v*r.x; acc[1][1] += h1v*r.y; acc[1][2] += h1v*r.z; acc[1][3] += h1v*r.w;
        }
        #pragma unroll
        for (int j = 0; j < 2; ++j) {
            int n = tn * 2 + j;
            #pragma unroll
            for (int l = 0; l < 4; ++l) sh2[n*65 + o0 + l] = elu_f(acc[j][l]);
        }
    }
    __syncthreads();

    {
        const int tn = tid >> 4;
        const int c0 = (tid & 15) * 8;
        float acc[2][8];
        #pragma unroll
        for (int j = 0; j < 2; ++j)
            #pragma unroll
            for (int l = 0; l < 8; ++l) acc[j][l] = sbf[c0 + l];
        #pragma unroll 8
        for (int k = 0; k < 64; ++k) {
            float4 w0 = *(const float4*)&sW[k*128 + c0];
            float4 w1 = *(const float4*)&sW[k*128 + c0 + 4];
            float h0 = sh2[(tn*2)*65 + k];
            float h1v = sh2[(tn*2+1)*65 + k];
            FMA8(acc[0], h0, w0, w1);
            FMA8(acc[1], h1v, w0, w1);
        }
        #pragma unroll
        for (int j = 0; j < 2; ++j) {
            size_t n = n0 + tn * 2 + j;
            float4 oA, oB;
            oA.x = elu_f(acc[j][0]); oA.y = elu_f(acc[j][1]); oA.z = elu_f(acc[j][2]); oA.w = elu_f(acc[j][3]);
            oB.x = elu_f(acc[j][4]); oB.y = elu_f(acc[j][5]); oB.z = elu_f(acc[j][6]); oB.w = elu_f(acc[j][7]);
            *(float4*)&out[n*128 + c0]     = oA;
            *(float4*)&out[n*128 + c0 + 4] = oB;
        }
    }
}

extern "C" void kernel_launch(void* const* d_in, const int* in_sizes, int n_in,
                              void* d_out, int out_size, void* d_ws, size_t ws_size,
                              hipStream_t stream)
{
    const float* x     = (const float*)d_in[0];
    const int*   ei    = (const int*)d_in[1];
    const float* ea    = (const float*)d_in[2];
    const float* W1a   = (const float*)d_in[3];
    const float* b1a   = (const float*)d_in[4];
    const float* W1b   = (const float*)d_in[5];
    const float* b1b   = (const float*)d_in[6];
    const float* root1 = (const float*)d_in[7];
    const float* bias1 = (const float*)d_in[8];
    const float* W2a   = (const float*)d_in[9];
    const float* b2a   = (const float*)d_in[10];
    const float* W2b   = (const float*)d_in[11];
    const float* b2b   = (const float*)d_in[12];
    const float* root2 = (const float*)d_in[13];
    const float* bias2 = (const float*)d_in[14];
    const float* Wf    = (const float*)d_in[15];
    const float* bf    = (const float*)d_in[16];
    float* out = (float*)d_out;

    float* ws    = (float*)d_ws;
    float* msg1  = ws;                           // 4,194,304 floats
    float* msg2  = ws + 4194304;                 // 4,194,304
    float* h1    = ws + 8388608;                 // 2,097,152
    short* BT    = (short*)(ws + 10485760);      // 589,824 shorts = 294,912 floats
    int*   cnt_i = (int*)(ws + 10780672);        // NN
    int*   startp= (int*)(ws + 10813440);        // NN
    int*   cursor= (int*)(ws + 10846208);        // NN
    int*   perm  = (int*)(ws + 10878976);        // NE
    // total ws use: ~43.8 MB

    hipMemsetAsync(cnt_i, 0, (size_t)NN * sizeof(int), stream);

    k_prep  <<<1024,      256, 0, stream>>>(W2b, BT);
    k_hist  <<<NE/256,    256, 0, stream>>>(ei, cnt_i);
    k_scan  <<<1,        1024, 0, stream>>>(cnt_i, startp, cursor);
    k_fill  <<<NE/256,    256, 0, stream>>>(ei, cursor, perm);
    k1_conv1<<<NE/256,    256, 0, stream>>>(x, ei, ea, perm, W1a, b1a, W1b, b1b, msg1);
    k2_node1<<<NN/64,     256, 0, stream>>>(msg1, startp, cnt_i, x, root1, bias1, h1);
    k3_mfma <<<NE/256,    256, 0, stream>>>(h1, ei, ea, perm, W2a, b2a, BT, b2b, msg2);
    k4_final<<<NN/32,     256, 0, stream>>>(msg2, startp, cnt_i, h1, root2, bias2, Wf, bf, out);
}

// Round 9
// 268.719 us; speedup vs baseline: 3.1470x; 1.0829x over previous
//
#include <hip/hip_runtime.h>
#include <math.h>

#define NN 32768
#define NE 65536

typedef __attribute__((ext_vector_type(8))) short bf16x8;
typedef __attribute__((ext_vector_type(4))) float f32x4;

__device__ __forceinline__ float elu_f(float v) {
    return v > 0.f ? v : (expf(v) - 1.f);
}
__device__ __forceinline__ unsigned short bf16_rn(float f) {
    unsigned u = __float_as_uint(f);
    return (unsigned short)((u + 0x7FFFu + ((u >> 16) & 1u)) >> 16);
}
__device__ __forceinline__ float bf16_to_f(unsigned short h) {
    return __uint_as_float(((unsigned)h) << 16);
}
// async global->LDS, 16B per lane; LDS dest = uniform base + lane*16 (HW)
__device__ __forceinline__ void gld16(const void* g, void* l) {
    __builtin_amdgcn_global_load_lds(
        (const __attribute__((address_space(1))) unsigned int*)g,
        (__attribute__((address_space(3))) unsigned int*)l, 16, 0, 0);
}

#define FMA8(Cj, aj, b0, b1) \
    Cj[0] += (aj)*(b0).x; Cj[1] += (aj)*(b0).y; Cj[2] += (aj)*(b0).z; Cj[3] += (aj)*(b0).w; \
    Cj[4] += (aj)*(b1).x; Cj[5] += (aj)*(b1).y; Cj[6] += (aj)*(b1).z; Cj[7] += (aj)*(b1).w;

// ---------------- fused prep (W2b/b2b/W1b bf16 hi-lo split) + dst histogram ----------------
// BT2 chunk c in [0,65): [c*9216 + o*72 + i] hi, +4608 lo.  c<64: W2b[c,i*64+o]; c==64: b2b[i*64+o]
// BT1 chunk c in [0,3):  [c*9216 + o*72 + k] hi, +4608 lo.  W1b[k, c*64+o]
__global__ void k_prep2(const float* __restrict__ W2b, const float* __restrict__ b2b,
                        const float* __restrict__ W1b, const int* __restrict__ ei,
                        short* __restrict__ BT2, short* __restrict__ BT1,
                        int* __restrict__ cnt) {
    int g = blockIdx.x * 256 + threadIdx.x;
    if (g < 262144) {
        float f = W2b[g];
        int o = g & 63, i = (g >> 6) & 63, k = g >> 12;
        unsigned short hi = bf16_rn(f);
        unsigned short lo = bf16_rn(f - bf16_to_f(hi));
        BT2[(size_t)k * 9216 + o * 72 + i]        = (short)hi;
        BT2[(size_t)k * 9216 + 4608 + o * 72 + i] = (short)lo;
    } else if (g < 266240) {
        int g2 = g - 262144;
        float f = b2b[g2];
        int o = g2 & 63, i = g2 >> 6;
        unsigned short hi = bf16_rn(f);
        unsigned short lo = bf16_rn(f - bf16_to_f(hi));
        BT2[(size_t)64 * 9216 + o * 72 + i]        = (short)hi;
        BT2[(size_t)64 * 9216 + 4608 + o * 72 + i] = (short)lo;
    } else if (g < 278528) {
        int g2 = g - 266240;
        float f = W1b[g2];
        int col = g2 % 192, k = g2 / 192;
        int c = col >> 6, o = col & 63;
        unsigned short hi = bf16_rn(f);
        unsigned short lo = bf16_rn(f - bf16_to_f(hi));
        BT1[c * 9216 + o * 72 + k]        = (short)hi;
        BT1[c * 9216 + 4608 + o * 72 + k] = (short)lo;
    } else {
        int e = g - 278528;       // < 65536
        atomicAdd(&cnt[ei[NE + e]], 1);
    }
}

// ---------------- exclusive scan over 32768 counts (single block) ----------------
__global__ __launch_bounds__(1024) void k_scan(const int* __restrict__ cnt,
                                               int* __restrict__ start,
                                               int* __restrict__ cursor) {
    __shared__ int wtot[16];
    const int t = threadIdx.x;
    const int lane = t & 63, wave = t >> 6;
    int local[32];
    const int base = t * 32;
    int s = 0;
    #pragma unroll
    for (int j = 0; j < 32; ++j) { local[j] = s; s += cnt[base + j]; }
    const int tot = s;
    int sc = tot;
    #pragma unroll
    for (int off = 1; off < 64; off <<= 1) {
        int v = __shfl_up(sc, off, 64);
        if (lane >= off) sc += v;
    }
    if (lane == 63) wtot[wave] = sc;
    __syncthreads();
    if (t == 0) {
        int run = 0;
        #pragma unroll
        for (int w = 0; w < 16; ++w) { int v = wtot[w]; wtot[w] = run; run += v; }
    }
    __syncthreads();
    const int tbase = wtot[wave] + (sc - tot);
    #pragma unroll
    for (int j = 0; j < 32; ++j) {
        int v = tbase + local[j];
        start[base + j] = v;
        cursor[base + j] = v;
    }
}

__global__ void k_fill(const int* __restrict__ ei, int* __restrict__ cursor,
                       int* __restrict__ perm) {
    int e = blockIdx.x * 256 + threadIdx.x;
    if (e < NE) {
        int d = ei[NE + e];
        int pos = atomicAdd(&cursor[d], 1);
        perm[pos] = e;
    }
}

// ---------------- layer-1 edge messages: MFMA, natural edge order ----------------
// msg1[e,o] = sum_c xs[e,c]*( hh[e,:]@W1b_c + b1b[c*64+o] ),  hh = relu(ea@W1a+b1a)
// 128 edges/block, 4 waves (wave: 32 edges = 2 row-tiles), A=hh recomputed+hi/lo in regs.
__global__ __launch_bounds__(256, 2) void k1_conv1(
    const float* __restrict__ x, const int* __restrict__ ei,
    const float* __restrict__ eatt,
    const float* __restrict__ W1a, const float* __restrict__ b1a,
    const short* __restrict__ BT1, const float* __restrict__ b1b,
    float* __restrict__ msg1)
{
    __shared__ __align__(16) short sBT1[3 * 9216];   // 55296 B
    __shared__ float sxs[128 * 4];
    __shared__ float sea[128 * 4];
    __shared__ float sW1a[192];
    __shared__ float sb1a[64];
    __shared__ float sb1b[192];

    const int tid = threadIdx.x;
    const int e0  = blockIdx.x * 128;
    const int wid = tid >> 6;
    const int lane = tid & 63;
    const int l15 = lane & 15, lhi = lane >> 4;

    // stage all 3 B-chunks async (54 KiB)
    {
        const char* src = (const char*)BT1;
        char* dst = (char*)&sBT1[0];
        for (int j = wid; j < 54; j += 4)
            gld16(src + j * 1024 + lane * 16, dst + j * 1024);
    }
    if (tid < 192) { sW1a[tid] = W1a[tid]; sb1b[tid] = b1b[tid]; }
    if (tid < 64)  sb1a[tid] = b1a[tid];
    if (tid < 128) {
        int e = e0 + tid;
        int s = ei[e];
        sxs[tid*4+0] = x[s*3+0];
        sxs[tid*4+1] = x[s*3+1];
        sxs[tid*4+2] = x[s*3+2];
        sea[tid*4+0] = eatt[e*3+0];
        sea[tid*4+1] = eatt[e*3+1];
        sea[tid*4+2] = eatt[e*3+2];
    }
    __syncthreads();

    // A-fragments: hh rows = wid*32+rt*16+l15, k = kc*32+lhi*8+j  (hi/lo)
    bf16x8 ah[2][2], al[2][2];
    #pragma unroll
    for (int rt = 0; rt < 2; ++rt) {
        const int arow = wid*32 + rt*16 + l15;
        const float a0 = sea[arow*4+0], a1 = sea[arow*4+1], a2 = sea[arow*4+2];
        #pragma unroll
        for (int kc = 0; kc < 2; ++kc) {
            const int kb = kc*32 + lhi*8;
            bf16x8 H, L;
            #pragma unroll
            for (int j = 0; j < 8; ++j) {
                int k = kb + j;
                float f = fmaxf(sb1a[k] + a0*sW1a[k] + a1*sW1a[64+k] + a2*sW1a[128+k], 0.f);
                unsigned short hh = bf16_rn(f);
                unsigned short ll = bf16_rn(f - bf16_to_f(hh));
                H[j] = (short)hh; L[j] = (short)ll;
            }
            ah[rt][kc] = H; al[rt][kc] = L;
        }
    }
    // xs for C-rows
    float xr[2][4][3];
    #pragma unroll
    for (int rt = 0; rt < 2; ++rt)
        #pragma unroll
        for (int r = 0; r < 4; ++r) {
            int crow = wid*32 + rt*16 + lhi*4 + r;
            xr[rt][r][0] = sxs[crow*4+0];
            xr[rt][r][1] = sxs[crow*4+1];
            xr[rt][r][2] = sxs[crow*4+2];
        }

    f32x4 acc[2][4];
    #pragma unroll
    for (int rt = 0; rt < 2; ++rt)
        #pragma unroll
        for (int ot = 0; ot < 4; ++ot) { acc[rt][ot][0]=0.f; acc[rt][ot][1]=0.f; acc[rt][ot][2]=0.f; acc[rt][ot][3]=0.f; }

    #pragma unroll
    for (int c = 0; c < 3; ++c) {
        const short* Bh = &sBT1[c * 9216];
        const short* Bl = Bh + 4608;
        #pragma unroll
        for (int ot = 0; ot < 4; ++ot) {
            const int ob = (ot*16 + l15)*72 + lhi*8;
            bf16x8 bh0 = *(const bf16x8*)&Bh[ob];
            bf16x8 bh1 = *(const bf16x8*)&Bh[ob + 32];
            bf16x8 bl0 = *(const bf16x8*)&Bl[ob];
            bf16x8 bl1 = *(const bf16x8*)&Bl[ob + 32];
            #pragma unroll
            for (int rt = 0; rt < 2; ++rt) {
                f32x4 t = {0.f, 0.f, 0.f, 0.f};
                t = __builtin_amdgcn_mfma_f32_16x16x32_bf16(ah[rt][0], bh0, t, 0, 0, 0);
                t = __builtin_amdgcn_mfma_f32_16x16x32_bf16(al[rt][0], bh0, t, 0, 0, 0);
                t = __builtin_amdgcn_mfma_f32_16x16x32_bf16(ah[rt][0], bl0, t, 0, 0, 0);
                t = __builtin_amdgcn_mfma_f32_16x16x32_bf16(ah[rt][1], bh1, t, 0, 0, 0);
                t = __builtin_amdgcn_mfma_f32_16x16x32_bf16(al[rt][1], bh1, t, 0, 0, 0);
                t = __builtin_amdgcn_mfma_f32_16x16x32_bf16(ah[rt][1], bl1, t, 0, 0, 0);
                #pragma unroll
                for (int r = 0; r < 4; ++r)
                    acc[rt][ot][r] += xr[rt][r][c] * t[r];
            }
        }
    }
    // bias: sum_c xs[c]*b1b[c*64+o], then store (natural edge order)
    #pragma unroll
    for (int rt = 0; rt < 2; ++rt) {
        #pragma unroll
        for (int ot = 0; ot < 4; ++ot) {
            const int o = ot*16 + l15;
            const float b0 = sb1b[o], b1 = sb1b[64+o], b2 = sb1b[128+o];
            #pragma unroll
            for (int r = 0; r < 4; ++r) {
                float v = acc[rt][ot][r] + xr[rt][r][0]*b0 + xr[rt][r][1]*b1 + xr[rt][r][2]*b2;
                int row = e0 + wid*32 + rt*16 + lhi*4 + r;
                msg1[(size_t)row * 64 + o] = v;
            }
        }
    }
}

// ---------------- layer-1 node update: segmented sum via perm gather ----------------
__global__ __launch_bounds__(256) void k2_node1(
    const float* __restrict__ msg1, const int* __restrict__ start,
    const int* __restrict__ cnt, const int* __restrict__ perm,
    const float* __restrict__ x, const float* __restrict__ root1,
    const float* __restrict__ bias1, float* __restrict__ h1)
{
    __shared__ float sR[192], sb[64];
    const int tid = threadIdx.x;
    if (tid < 192) sR[tid] = root1[tid];
    if (tid < 64)  sb[tid] = bias1[tid];
    __syncthreads();
    const int n = blockIdx.x * 64 + (tid >> 2);
    const int c = (tid & 3) * 16;
    const int st = start[n], num = cnt[n];
    float acc[16];
    #pragma unroll
    for (int l = 0; l < 16; ++l) acc[l] = 0.f;
    for (int d = 0; d < num; ++d) {
        const int row = perm[st + d];
        const float* rp = &msg1[(size_t)row * 64 + c];
        #pragma unroll
        for (int q = 0; q < 4; ++q) {
            float4 v = *(const float4*)(rp + q * 4);
            acc[q*4+0] += v.x; acc[q*4+1] += v.y; acc[q*4+2] += v.z; acc[q*4+3] += v.w;
        }
    }
    const float inv = 1.f / fmaxf((float)num, 1.f);
    const float x0 = x[n*3+0], x1 = x[n*3+1], x2 = x[n*3+2];
    float* hp = &h1[(size_t)n * 64 + c];
    #pragma unroll
    for (int q = 0; q < 4; ++q) {
        float4 ov;
        float* o4 = (float*)&ov;
        #pragma unroll
        for (int l = 0; l < 4; ++l) {
            int o = c + q*4 + l;
            float v = acc[q*4+l] * inv + sb[o] + x0*sR[o] + x1*sR[64+o] + x2*sR[128+o];
            o4[l] = elu_f(v);
        }
        *(float4*)(hp + q*4) = ov;
    }
}

// ---------------- layer-2 edge messages: MFMA, v-in-registers, u recomputed ----------------
// msg2[e,o] = sum_k u[e,k]*( v[e,:]@Wk[:,o] ) + v[e,:]@b2b_mat[:,o]
// A = v = h1[src] (hi/lo frags, regs); B = BT2 chunk per k (65 chunks incl. bias), dbuf via global_load_lds;
// u[e,k] = relu(b2a[k]+ea@W2a[:,k]) recomputed per iter on VALU. 128 edges/block, 2 blocks/CU.
__global__ __launch_bounds__(256, 2) void k3_mfma(
    const float* __restrict__ h1, const int* __restrict__ ei,
    const float* __restrict__ eatt,
    const float* __restrict__ W2a, const float* __restrict__ b2a,
    const short* __restrict__ BT2,
    float* __restrict__ msg2)
{
    __shared__ __align__(16) float sV[128 * 68];     // 34816 B (prologue only)
    __shared__ __align__(16) short sB[2][9216];      // 36864 B double buffer
    __shared__ float sea[128 * 4];
    __shared__ float sW2a[192];
    __shared__ float sb2a[64];

    const int tid = threadIdx.x;
    const int e0  = blockIdx.x * 128;
    const int wid = tid >> 6;
    const int lane = tid & 63;
    const int l15 = lane & 15, lhi = lane >> 4;

    // issue chunk-0 staging ASAP (async)
    {
        const char* src = (const char*)BT2;
        char* dst = (char*)&sB[0][0];
        for (int j = wid; j < 18; j += 4)
            gld16(src + j * 1024 + lane * 16, dst + j * 1024);
    }
    if (tid < 192) sW2a[tid] = W2a[tid];
    if (tid < 64)  sb2a[tid] = b2a[tid];
    if (tid < 128) {
        int e = e0 + tid;
        sea[tid*4+0] = eatt[e*3+0];
        sea[tid*4+1] = eatt[e*3+1];
        sea[tid*4+2] = eatt[e*3+2];
    }
    // gather v rows (h1[src]) into sV
    {
        const int edge = tid >> 1, half = tid & 1;
        const int s = ei[e0 + edge];
        const float* row = h1 + (size_t)s * 64 + half * 32;
        float* dst = &sV[edge * 68 + half * 32];
        #pragma unroll
        for (int q = 0; q < 8; ++q)
            *(float4*)(dst + q*4) = *(const float4*)(row + q*4);
    }
    __syncthreads();   // drains vmcnt: sB[0] ready, sV ready

    // A-fragments (v) hi/lo, rows = wid*32+rt*16+l15, i = kc*32+lhi*8+j
    bf16x8 vh[2][2], vl[2][2];
    #pragma unroll
    for (int rt = 0; rt < 2; ++rt)
        #pragma unroll
        for (int kc = 0; kc < 2; ++kc) {
            const float* p = &sV[(wid*32 + rt*16 + l15)*68 + kc*32 + lhi*8];
            bf16x8 H, L;
            #pragma unroll
            for (int j = 0; j < 8; ++j) {
                float f = p[j];
                unsigned short hh = bf16_rn(f);
                unsigned short ll = bf16_rn(f - bf16_to_f(hh));
                H[j] = (short)hh; L[j] = (short)ll;
            }
            vh[rt][kc] = H; vl[rt][kc] = L;
        }
    // ea for C-rows (u-scale inputs)
    float er[2][4][3];
    #pragma unroll
    for (int rt = 0; rt < 2; ++rt)
        #pragma unroll
        for (int r = 0; r < 4; ++r) {
            int row = wid*32 + rt*16 + lhi*4 + r;
            er[rt][r][0] = sea[row*4+0];
            er[rt][r][1] = sea[row*4+1];
            er[rt][r][2] = sea[row*4+2];
        }

    f32x4 acc[2][4];
    #pragma unroll
    for (int rt = 0; rt < 2; ++rt)
        #pragma unroll
        for (int ot = 0; ot < 4; ++ot) { acc[rt][ot][0]=0.f; acc[rt][ot][1]=0.f; acc[rt][ot][2]=0.f; acc[rt][ot][3]=0.f; }

    int cur = 0;
    for (int k = 0; k <= 64; ++k) {
        // async prefetch of next chunk into the other buffer
        if (k < 64) {
            const char* src = (const char*)(BT2 + (size_t)(k + 1) * 9216);
            char* dst = (char*)&sB[cur ^ 1][0];
            for (int j = wid; j < 18; j += 4)
                gld16(src + j * 1024 + lane * 16, dst + j * 1024);
        }
        // u-scales for this k (k==64 -> bias chunk, scale 1)
        float us[2][4];
        if (k < 64) {
            const float wa = sW2a[k], wb = sW2a[64+k], wc = sW2a[128+k], bb = sb2a[k];
            #pragma unroll
            for (int rt = 0; rt < 2; ++rt)
                #pragma unroll
                for (int r = 0; r < 4; ++r)
                    us[rt][r] = fmaxf(bb + er[rt][r][0]*wa + er[rt][r][1]*wb + er[rt][r][2]*wc, 0.f);
        } else {
            #pragma unroll
            for (int rt = 0; rt < 2; ++rt)
                #pragma unroll
                for (int r = 0; r < 4; ++r) us[rt][r] = 1.f;
        }
        const short* Bh = &sB[cur][0];
        const short* Bl = &sB[cur][4608];
        #pragma unroll
        for (int ot = 0; ot < 4; ++ot) {
            const int ob = (ot*16 + l15)*72 + lhi*8;
            bf16x8 bh0 = *(const bf16x8*)&Bh[ob];
            bf16x8 bh1 = *(const bf16x8*)&Bh[ob + 32];
            bf16x8 bl0 = *(const bf16x8*)&Bl[ob];
            bf16x8 bl1 = *(const bf16x8*)&Bl[ob + 32];
            #pragma unroll
            for (int rt = 0; rt < 2; ++rt) {
                f32x4 t = {0.f, 0.f, 0.f, 0.f};
                t = __builtin_amdgcn_mfma_f32_16x16x32_bf16(vh[rt][0], bh0, t, 0, 0, 0);
                t = __builtin_amdgcn_mfma_f32_16x16x32_bf16(vl[rt][0], bh0, t, 0, 0, 0);
                t = __builtin_amdgcn_mfma_f32_16x16x32_bf16(vh[rt][0], bl0, t, 0, 0, 0);
                t = __builtin_amdgcn_mfma_f32_16x16x32_bf16(vh[rt][1], bh1, t, 0, 0, 0);
                t = __builtin_amdgcn_mfma_f32_16x16x32_bf16(vl[rt][1], bh1, t, 0, 0, 0);
                t = __builtin_amdgcn_mfma_f32_16x16x32_bf16(vh[rt][1], bl1, t, 0, 0, 0);
                #pragma unroll
                for (int r = 0; r < 4; ++r)
                    acc[rt][ot][r] += us[rt][r] * t[r];
            }
        }
        __syncthreads();   // drains vmcnt: prefetch landed; all waves done with sB[cur]
        if (k < 64) cur ^= 1;
    }

    // store (natural edge order): row = e0+wid*32+rt*16+lhi*4+r, col = ot*16+l15
    #pragma unroll
    for (int rt = 0; rt < 2; ++rt)
        #pragma unroll
        for (int ot = 0; ot < 4; ++ot) {
            const int o = ot*16 + l15;
            #pragma unroll
            for (int r = 0; r < 4; ++r) {
                int row = e0 + wid*32 + rt*16 + lhi*4 + r;
                msg2[(size_t)row * 64 + o] = acc[rt][ot][r];
            }
        }
}

// ---------------- layer-2 node update + FC, fused, perm-gather segmented sum ----------------
__global__ __launch_bounds__(256, 2) void k4_final(
    const float* __restrict__ msg2, const int* __restrict__ start,
    const int* __restrict__ cnt, const int* __restrict__ perm,
    const float* __restrict__ h1,
    const float* __restrict__ root2, const float* __restrict__ bias2,
    const float* __restrict__ Wf, const float* __restrict__ bf,
    float* __restrict__ out)
{
    __shared__ float sh1[32 * 65];
    __shared__ float sh2[32 * 65];
    __shared__ float sR[64 * 64];
    __shared__ float sW[64 * 128];
    __shared__ float sb2[64];
    __shared__ float sbf[128];
    __shared__ float sinv[32];
    __shared__ int   sstart[32];
    __shared__ int   scnt[32];
    const int tid = threadIdx.x;
    const int n0 = blockIdx.x * 32;

    for (int u = tid; u < 64*64/4; u += 256) ((float4*)sR)[u] = ((const float4*)root2)[u];
    for (int u = tid; u < 64*128/4; u += 256) ((float4*)sW)[u] = ((const float4*)Wf)[u];
    if (tid < 64)  sb2[tid] = bias2[tid];
    if (tid < 128) sbf[tid] = bf[tid];
    if (tid < 32) {
        int n = n0 + tid;
        int cc = cnt[n];
        sstart[tid] = start[n];
        scnt[tid] = cc;
        sinv[tid] = 1.f / fmaxf((float)cc, 1.f);
    }
    for (int u = tid; u < 32 * 16; u += 256) {
        int n = u >> 4, i4 = (u & 15) * 4;
        float4 v = *(const float4*)&h1[(size_t)(n0 + n) * 64 + i4];
        sh1[n*65+i4] = v.x; sh1[n*65+i4+1] = v.y; sh1[n*65+i4+2] = v.z; sh1[n*65+i4+3] = v.w;
    }
    __syncthreads();

    {
        const int tn = tid >> 4;
        const int o0 = (tid & 15) * 4;
        float acc[2][4];
        #pragma unroll
        for (int j = 0; j < 2; ++j) {
            int ln = tn * 2 + j;
            int st = sstart[ln], num = scnt[ln];
            float4 a = {0.f, 0.f, 0.f, 0.f};
            for (int d = 0; d < num; ++d) {
                int row = perm[st + d];
                float4 s = *(const float4*)&msg2[(size_t)row * 64 + o0];
                a.x += s.x; a.y += s.y; a.z += s.z; a.w += s.w;
            }
            float inv = sinv[ln];
            acc[j][0] = a.x*inv + sb2[o0+0];
            acc[j][1] = a.y*inv + sb2[o0+1];
            acc[j][2] = a.z*inv + sb2[o0+2];
            acc[j][3] = a.w*inv + sb2[o0+3];
        }
        #pragma unroll 8
        for (int k = 0; k < 64; ++k) {
            float4 r = *(const float4*)&sR[k*64 + o0];
            float h0 = sh1[(tn*2)*65 + k];
            float h1v = sh1[(tn*2+1)*65 + k];
            acc[0][0] += h0*r.x; acc[0][1] += h0*r.y; acc[0][2] += h0*r.z; acc[0][3] += h0*r.w;
            acc[1][0] += h1v*r.x; acc[1][1] += h1v*r.y; acc[1][2] += h1v*r.z; acc[1][3] += h1v*r.w;
        }
        #pragma unroll
        for (int j = 0; j < 2; ++j) {
            int n = tn * 2 + j;
            #pragma unroll
            for (int l = 0; l < 4; ++l) sh2[n*65 + o0 + l] = elu_f(acc[j][l]);
        }
    }
    __syncthreads();

    {
        const int tn = tid >> 4;
        const int c0 = (tid & 15) * 8;
        float acc[2][8];
        #pragma unroll
        for (int j = 0; j < 2; ++j)
            #pragma unroll
            for (int l = 0; l < 8; ++l) acc[j][l] = sbf[c0 + l];
        #pragma unroll 8
        for (int k = 0; k < 64; ++k) {
            float4 w0 = *(const float4*)&sW[k*128 + c0];
            float4 w1 = *(const float4*)&sW[k*128 + c0 + 4];
            float h0 = sh2[(tn*2)*65 + k];
            float h1v = sh2[(tn*2+1)*65 + k];
            FMA8(acc[0], h0, w0, w1);
            FMA8(acc[1], h1v, w0, w1);
        }
        #pragma unroll
        for (int j = 0; j < 2; ++j) {
            size_t n = n0 + tn * 2 + j;
            float4 oA, oB;
            oA.x = elu_f(acc[j][0]); oA.y = elu_f(acc[j][1]); oA.z = elu_f(acc[j][2]); oA.w = elu_f(acc[j][3]);
            oB.x = elu_f(acc[j][4]); oB.y = elu_f(acc[j][5]); oB.z = elu_f(acc[j][6]); oB.w = elu_f(acc[j][7]);
            *(float4*)&out[n*128 + c0]     = oA;
            *(float4*)&out[n*128 + c0 + 4] = oB;
        }
    }
}

extern "C" void kernel_launch(void* const* d_in, const int* in_sizes, int n_in,
                              void* d_out, int out_size, void* d_ws, size_t ws_size,
                              hipStream_t stream)
{
    const float* x     = (const float*)d_in[0];
    const int*   ei    = (const int*)d_in[1];
    const float* ea    = (const float*)d_in[2];
    const float* W1a   = (const float*)d_in[3];
    const float* b1a   = (const float*)d_in[4];
    const float* W1b   = (const float*)d_in[5];
    const float* b1b   = (const float*)d_in[6];
    const float* root1 = (const float*)d_in[7];
    const float* bias1 = (const float*)d_in[8];
    const float* W2a   = (const float*)d_in[9];
    const float* b2a   = (const float*)d_in[10];
    const float* W2b   = (const float*)d_in[11];
    const float* b2b   = (const float*)d_in[12];
    const float* root2 = (const float*)d_in[13];
    const float* bias2 = (const float*)d_in[14];
    const float* Wf    = (const float*)d_in[15];
    const float* bf    = (const float*)d_in[16];
    float* out = (float*)d_out;

    float* ws    = (float*)d_ws;
    float* msg1  = ws;                            // 4,194,304 f
    float* msg2  = ws + 4194304;                  // 4,194,304 f
    float* h1    = ws + 8388608;                  // 2,097,152 f
    short* BT2   = (short*)(ws + 10485760);       // 599,040 sh = 299,520 f
    short* BT1   = (short*)(ws + 10785280);       // 27,648 sh = 13,824 f
    int*   cnt_i = (int*)(ws + 10799104);         // NN
    int*   startp= (int*)(ws + 10831872);         // NN
    int*   cursor= (int*)(ws + 10864640);         // NN
    int*   perm  = (int*)(ws + 10897408);         // NE
    // total ws use ~41.9 MB

    hipMemsetAsync(cnt_i, 0, (size_t)NN * sizeof(int), stream);

    k_prep2 <<<1344,      256, 0, stream>>>(W2b, b2b, W1b, ei, BT2, BT1, cnt_i);
    k_scan  <<<1,        1024, 0, stream>>>(cnt_i, startp, cursor);
    k_fill  <<<NE/256,    256, 0, stream>>>(ei, cursor, perm);
    k1_conv1<<<NE/128,    256, 0, stream>>>(x, ei, ea, W1a, b1a, BT1, b1b, msg1);
    k2_node1<<<NN/64,     256, 0, stream>>>(msg1, startp, cnt_i, perm, x, root1, bias1, h1);
    k3_mfma <<<NE/128,    256, 0, stream>>>(h1, ei, ea, W2a, b2a, BT2, msg2);
    k4_final<<<NN/32,     256, 0, stream>>>(msg2, startp, cnt_i, perm, h1, root2, bias2, Wf, bf, out);
}